// Round 2
// baseline (1232.137 us; speedup 1.0000x reference)
//
#include <hip/hip_runtime.h>
#include <hip/hip_bf16.h>

#define NRES 768
#define CZ   128
#define NPIX (NRES * NRES)

typedef __bf16 bf16x8 __attribute__((ext_vector_type(8)));
typedef float  f32x4  __attribute__((ext_vector_type(4)));

__device__ __forceinline__ unsigned short f2bf(float f) {
    unsigned u = __float_as_uint(f);
    u += 0x7FFFu + ((u >> 16) & 1u);   // round-to-nearest-even
    return (unsigned short)(u >> 16);
}
__device__ __forceinline__ float bf2f(unsigned short s) {
    return __uint_as_float(((unsigned)s) << 16);
}
__device__ __forceinline__ float sigm(float x) { return 1.0f / (1.0f + __expf(-x)); }
__device__ __forceinline__ f32x4 fzero() { f32x4 z = {0.f, 0.f, 0.f, 0.f}; return z; }

// global -> LDS direct DMA, 16B per lane. LDS dest is wave-uniform base;
// HW adds lane*16. Proper addrspacecasts (NOT integer truncation).
typedef __attribute__((address_space(3))) unsigned int       lds_u32;
typedef const __attribute__((address_space(1))) unsigned int glb_u32;
__device__ __forceinline__ void async16(void* lds, const void* g) {
    __builtin_amdgcn_global_load_lds((glb_u32*)g, (lds_u32*)lds, 16, 0, 0);
}

// ---------------------------------------------------------------------------
// Pack weights to bf16. Wcat rows: [0,256)=proj, [256,512)=gate, [512,640)=gl.
__global__ void k_pack(const float* __restrict__ pw, const float* __restrict__ gw,
                       const float* __restrict__ glw, const float* __restrict__ pb,
                       const float* __restrict__ gb, const float* __restrict__ glb,
                       const float* __restrict__ ow,
                       unsigned short* __restrict__ Wcat, float* __restrict__ bcat,
                       unsigned short* __restrict__ Wout) {
    int idx = blockIdx.x * 256 + threadIdx.x;
    if (idx < 640 * 128) {
        int row = idx >> 7;
        float v = (row < 256) ? pw[idx] : (row < 512) ? gw[idx - 256 * 128] : glw[idx - 512 * 128];
        Wcat[idx] = f2bf(v);
    }
    if (idx < 128 * 128) Wout[idx] = f2bf(ow[idx]);
    if (idx < 640) bcat[idx] = (idx < 256) ? pb[idx] : (idx < 512) ? gb[idx - 256] : glb[idx - 512];
}

// ---------------------------------------------------------------------------
// Kernel A: LN(act) -> GEMM vs packed weights -> gated epilogue.
// 64 pixels/block, 256 threads (4 waves, 2x2 wave grid).
// left_t/right_t: [128 ch][NPIX] bf16 (transposed). gate_out: [NPIX][128] bf16.
__global__ void __launch_bounds__(256)
k_lnproj(const float* __restrict__ act, const float* __restrict__ mask,
         const float* __restrict__ lnw, const float* __restrict__ lnb,
         const unsigned short* __restrict__ Wcat, const float* __restrict__ bcat,
         unsigned short* __restrict__ left_t, unsigned short* __restrict__ right_t,
         unsigned short* __restrict__ gate_out) {
    __shared__ unsigned short sA[64 * 128];   // LN'd act tile, XOR-swizzled
    __shared__ unsigned short sO[64 * 80];    // epilogue bounce
    __shared__ float smask[64];

    const int t = threadIdx.x;
    const int lane = t & 63;
    const int w = t >> 6;
    const int m0 = blockIdx.x * 64;

    // Phase 1: LayerNorm of 64 rows (4 threads/row)
    {
        const int r = t >> 2, q = t & 3;
        const float* src = act + (size_t)(m0 + r) * CZ + q * 32;
        float x[32];
        float s = 0.f, s2 = 0.f;
#pragma unroll
        for (int jj = 0; jj < 8; ++jj) {
            float4 v = *(const float4*)(src + jj * 4);
            x[jj * 4 + 0] = v.x; x[jj * 4 + 1] = v.y; x[jj * 4 + 2] = v.z; x[jj * 4 + 3] = v.w;
            s  += v.x + v.y + v.z + v.w;
            s2 += v.x * v.x + v.y * v.y + v.z * v.z + v.w * v.w;
        }
        s += __shfl_xor(s, 1);  s2 += __shfl_xor(s2, 1);
        s += __shfl_xor(s, 2);  s2 += __shfl_xor(s2, 2);
        const float mu = s * (1.f / 128.f);
        const float rstd = rsqrtf(s2 * (1.f / 128.f) - mu * mu + 1e-5f);
#pragma unroll
        for (int jj = 0; jj < 16; ++jj) {
            const int c = q * 32 + jj * 2;
            const float y0 = (x[jj * 2 + 0] - mu) * rstd * lnw[c]     + lnb[c];
            const float y1 = (x[jj * 2 + 1] - mu) * rstd * lnw[c + 1] + lnb[c + 1];
            const unsigned pk = (unsigned)f2bf(y0) | ((unsigned)f2bf(y1) << 16);
            int byte = r * 256 + c * 2;  byte ^= (r & 7) << 4;
            *(unsigned*)((char*)sA + byte) = pk;
        }
        if (q == 0) smask[r] = mask[m0 + r];
    }
    __syncthreads();

    const int wm = w >> 1, wn = w & 1;
    const int l15 = lane & 15, l4 = lane >> 4;

    // 6 column groups: g0,g1 -> left; g2,g3 -> right; g4,g5 -> gating_linear
#pragma unroll
    for (int g = 0; g < 6; ++g) {
        const bool pair = (g < 4);
        const int bp0 = pair ? g * 64 : (512 + (g - 4) * 64);
        const int bg0 = 256 + g * 64;
        f32x4 accp[2][2], accg[2][2];
#pragma unroll
        for (int a_ = 0; a_ < 2; ++a_)
#pragma unroll
            for (int b_ = 0; b_ < 2; ++b_) { accp[a_][b_] = fzero(); accg[a_][b_] = fzero(); }

#pragma unroll
        for (int kk = 0; kk < 4; ++kk) {
            const int kb = kk * 32 + l4 * 8;
            bf16x8 a[2], bp[2], bg[2];
#pragma unroll
            for (int f = 0; f < 2; ++f) {
                const int row = wm * 32 + f * 16 + l15;
                int byte = row * 256 + kb * 2;  byte ^= (row & 7) << 4;
                a[f] = *(const bf16x8*)((const char*)sA + byte);
                const int o = wn * 32 + f * 16 + l15;
                bp[f] = *(const bf16x8*)(Wcat + (size_t)(bp0 + o) * CZ + kb);
                if (pair) bg[f] = *(const bf16x8*)(Wcat + (size_t)(bg0 + o) * CZ + kb);
            }
#pragma unroll
            for (int fm = 0; fm < 2; ++fm)
#pragma unroll
                for (int fn = 0; fn < 2; ++fn) {
                    accp[fm][fn] = __builtin_amdgcn_mfma_f32_16x16x32_bf16(a[fm], bp[fn], accp[fm][fn], 0, 0, 0);
                    if (pair)
                        accg[fm][fn] = __builtin_amdgcn_mfma_f32_16x16x32_bf16(a[fm], bg[fn], accg[fm][fn], 0, 0, 0);
                }
        }
        __syncthreads();   // protect sO from previous group's readers
        if (pair) {
            // sO[ch][m]
#pragma unroll
            for (int fm = 0; fm < 2; ++fm)
#pragma unroll
                for (int fn = 0; fn < 2; ++fn) {
                    const int chl = wn * 32 + fn * 16 + l15;
                    const float pb_ = bcat[bp0 + chl];
                    const float gb_ = bcat[bg0 + chl];
#pragma unroll
                    for (int r = 0; r < 4; ++r) {
                        const int ml = wm * 32 + fm * 16 + l4 * 4 + r;
                        const float val = smask[ml] * (accp[fm][fn][r] + pb_) * sigm(accg[fm][fn][r] + gb_);
                        sO[chl * 80 + ml] = f2bf(val);
                    }
                }
        } else {
            // sO[m][ch]
#pragma unroll
            for (int fm = 0; fm < 2; ++fm)
#pragma unroll
                for (int fn = 0; fn < 2; ++fn) {
                    const int chl = wn * 32 + fn * 16 + l15;
                    const float b_ = bcat[bp0 + chl];
#pragma unroll
                    for (int r = 0; r < 4; ++r) {
                        const int ml = wm * 32 + fm * 16 + l4 * 4 + r;
                        sO[ml * 80 + chl] = f2bf(sigm(accp[fm][fn][r] + b_));
                    }
                }
        }
        __syncthreads();
        if (pair) {
            const int ch = t >> 2, mseg = (t & 3) * 16;
            unsigned short* dst = ((g < 2) ? left_t : right_t)
                                + (size_t)((g & 1) * 64 + ch) * NPIX + m0 + mseg;
            uint4 v0 = *(const uint4*)&sO[ch * 80 + mseg];
            uint4 v1 = *(const uint4*)&sO[ch * 80 + mseg + 8];
            *(uint4*)dst = v0;
            *(uint4*)(dst + 8) = v1;
        } else {
            const int r_ = t >> 2, cseg = (t & 3) * 16;
            unsigned short* dst = gate_out + (size_t)(m0 + r_) * CZ + (g - 4) * 64 + cseg;
            uint4 v0 = *(const uint4*)&sO[r_ * 80 + cseg];
            uint4 v1 = *(const uint4*)&sO[r_ * 80 + cseg + 8];
            *(uint4*)dst = v0;
            *(uint4*)(dst + 8) = v1;
        }
    }
}

// ---------------------------------------------------------------------------
// Kernel B: per-channel NT GEMM tri_c = L_c * R_c^T  (m97 structure).
// 128x128 tile, BK=32, 4 waves, global_load_lds width-16 staging.
// XCD-bijective block swizzle: all 36 tiles of a channel on one XCD.
__global__ void __launch_bounds__(256)
k_tri(const unsigned short* __restrict__ left_t,
      const unsigned short* __restrict__ right_t,
      unsigned short* __restrict__ tri) {
    __shared__ unsigned short sA[128 * 32];
    __shared__ unsigned short sB[128 * 32];

    const int t = threadIdx.x, lane = t & 63, w = t >> 6;
    const int bx = blockIdx.x;                  // 4608 = 8 XCD * 16 ch * 36 tiles
    const int xcd = bx & 7, slot = bx >> 3;
    const int c = xcd + 8 * (slot / 36);
    const int tile = slot % 36;
    const int ti = tile / 6, tj = tile % 6;

    const unsigned short* Lc = left_t  + (size_t)c * NPIX + (size_t)(ti * 128) * NRES;
    const unsigned short* Rc = right_t + (size_t)c * NPIX + (size_t)(tj * 128) * NRES;
    unsigned short* Tc = tri + (size_t)c * NPIX;

    const int wm = w >> 1, wn = w & 1;
    const int l15 = lane & 15, l4 = lane >> 4;
    const int srow = lane >> 2, kch = lane & 3;

    f32x4 acc[4][4];
#pragma unroll
    for (int i_ = 0; i_ < 4; ++i_)
#pragma unroll
        for (int j_ = 0; j_ < 4; ++j_) acc[i_][j_] = fzero();

#pragma unroll 1
    for (int k0 = 0; k0 < NRES; k0 += 32) {
#pragma unroll
        for (int q = 0; q < 2; ++q) {
            const int rowb = w * 32 + q * 16;
            async16(&sA[(size_t)rowb * 32], Lc + (size_t)(rowb + srow) * NRES + k0 + kch * 8);
            async16(&sB[(size_t)rowb * 32], Rc + (size_t)(rowb + srow) * NRES + k0 + kch * 8);
        }
        __syncthreads();   // drains vmcnt (gll) + lgkmcnt
        bf16x8 a[4], b[4];
        const int kb = l4 * 8;
#pragma unroll
        for (int f = 0; f < 4; ++f) {
            a[f] = *(const bf16x8*)&sA[(wm * 64 + f * 16 + l15) * 32 + kb];
            b[f] = *(const bf16x8*)&sB[(wn * 64 + f * 16 + l15) * 32 + kb];
        }
#pragma unroll
        for (int fm = 0; fm < 4; ++fm)
#pragma unroll
            for (int fn = 0; fn < 4; ++fn)
                acc[fm][fn] = __builtin_amdgcn_mfma_f32_16x16x32_bf16(a[fm], b[fn], acc[fm][fn], 0, 0, 0);
        __syncthreads();
    }

#pragma unroll
    for (int fm = 0; fm < 4; ++fm)
#pragma unroll
        for (int fn = 0; fn < 4; ++fn) {
            const int col = tj * 128 + wn * 64 + fn * 16 + l15;
#pragma unroll
            for (int r = 0; r < 4; ++r) {
                const int row = ti * 128 + wm * 64 + fm * 16 + l4 * 4 + r;
                Tc[(size_t)row * NRES + col] = f2bf(acc[fm][fn][r]);
            }
        }
}

// ---------------------------------------------------------------------------
// Kernel C: per-pixel LN over c of tri, out-projection MFMA, gate, f32 out.
// Block = 128 pixels (one i, 128 consecutive j), 256 threads.
__global__ void __launch_bounds__(256)
k_final(const unsigned short* __restrict__ tri,
        const unsigned short* __restrict__ gate_out,
        const float* __restrict__ cnw, const float* __restrict__ cnb,
        const unsigned short* __restrict__ Wout, const float* __restrict__ ob,
        float* __restrict__ out) {
    __shared__ unsigned short sT[128 * 136];  // [c][j], 8-elem XOR swizzle on j
    __shared__ unsigned short sX[128 * 128];  // LN'd, [j][c], byte XOR swizzle
    __shared__ float sS[2][128], sQ[2][128], sMu[128], sRs[128];

    const int t = threadIdx.x, lane = t & 63, w = t >> 6;
    const int i = blockIdx.x / 6;
    const int j0 = (blockIdx.x % 6) * 128;
    const size_t pixbase = (size_t)i * NRES + j0;

    // load tri[c][i][j0..j0+128) -> sT
    {
        const int c = t >> 1, jseg = (t & 1) * 64;
        const unsigned short* src = tri + (size_t)c * NPIX + pixbase + jseg;
        const int cx = (c & 7) << 3;
#pragma unroll
        for (int q = 0; q < 8; ++q) {
            uint4 v = *(const uint4*)(src + q * 8);
            *(uint4*)&sT[c * 136 + ((jseg + q * 8) ^ cx)] = v;
        }
    }
    __syncthreads();
    // per-pixel stats (2 threads/pixel)
    {
        const int j = t & 127, h = t >> 7;
        float s = 0.f, s2 = 0.f;
#pragma unroll
        for (int cc = 0; cc < 64; ++cc) {
            const int c = h * 64 + cc;
            const float v = bf2f(sT[c * 136 + (j ^ ((c & 7) << 3))]);
            s += v; s2 += v * v;
        }
        sS[h][j] = s; sQ[h][j] = s2;
    }
    __syncthreads();
    if (t < 128) {
        const float s = sS[0][t] + sS[1][t];
        const float s2 = sQ[0][t] + sQ[1][t];
        const float mu = s * (1.f / 128.f);
        sMu[t] = mu;
        sRs[t] = rsqrtf(s2 * (1.f / 128.f) - mu * mu + 1e-5f);
    }
    __syncthreads();
    // normalize -> sX[j][c] bf16
    {
        const int j = t >> 1, cs = (t & 1) * 64;
        const float mu = sMu[j], rs = sRs[j];
#pragma unroll
        for (int cc = 0; cc < 64; cc += 2) {
            const int c0 = cs + cc, c1 = c0 + 1;
            const float v0 = (bf2f(sT[c0 * 136 + (j ^ ((c0 & 7) << 3))]) - mu) * rs * cnw[c0] + cnb[c0];
            const float v1 = (bf2f(sT[c1 * 136 + (j ^ ((c1 & 7) << 3))]) - mu) * rs * cnw[c1] + cnb[c1];
            const unsigned pk = (unsigned)f2bf(v0) | ((unsigned)f2bf(v1) << 16);
            int byte = j * 256 + c0 * 2;  byte ^= (j & 7) << 4;
            *(unsigned*)((char*)sX + byte) = pk;
        }
    }
    __syncthreads();

    const int wm = w >> 1, wn = w & 1;
    const int l15 = lane & 15, l4 = lane >> 4;
    f32x4 acc[4][4];
#pragma unroll
    for (int i_ = 0; i_ < 4; ++i_)
#pragma unroll
        for (int j_ = 0; j_ < 4; ++j_) acc[i_][j_] = fzero();

#pragma unroll
    for (int kk = 0; kk < 4; ++kk) {
        const int kb = kk * 32 + l4 * 8;
        bf16x8 a[4], b[4];
#pragma unroll
        for (int f = 0; f < 4; ++f) {
            const int row = wm * 64 + f * 16 + l15;
            int byte = row * 256 + kb * 2;  byte ^= (row & 7) << 4;
            a[f] = *(const bf16x8*)((const char*)sX + byte);
            b[f] = *(const bf16x8*)(Wout + (size_t)(wn * 64 + f * 16 + l15) * CZ + kb);
        }
#pragma unroll
        for (int fm = 0; fm < 4; ++fm)
#pragma unroll
            for (int fn = 0; fn < 4; ++fn)
                acc[fm][fn] = __builtin_amdgcn_mfma_f32_16x16x32_bf16(a[fm], b[fn], acc[fm][fn], 0, 0, 0);
    }
#pragma unroll
    for (int fm = 0; fm < 4; ++fm)
#pragma unroll
        for (int fn = 0; fn < 4; ++fn) {
            const int o = wn * 64 + fn * 16 + l15;
            const float bo = ob[o];
#pragma unroll
            for (int r = 0; r < 4; ++r) {
                const int j = wm * 64 + fm * 16 + l4 * 4 + r;
                const size_t m = pixbase + j;
                out[m * CZ + o] = (acc[fm][fn][r] + bo) * bf2f(gate_out[m * CZ + o]);
            }
        }
}

// ---------------------------------------------------------------------------
extern "C" void kernel_launch(void* const* d_in, const int* in_sizes, int n_in,
                              void* d_out, int out_size, void* d_ws, size_t ws_size,
                              hipStream_t stream) {
    (void)in_sizes; (void)n_in; (void)out_size; (void)ws_size;
    const float* act  = (const float*)d_in[0];
    const float* mask = (const float*)d_in[1];
    const float* lnw  = (const float*)d_in[2];
    const float* lnb  = (const float*)d_in[3];
    const float* pw   = (const float*)d_in[4];
    const float* pb   = (const float*)d_in[5];
    const float* gw   = (const float*)d_in[6];
    const float* gb   = (const float*)d_in[7];
    const float* cnw  = (const float*)d_in[8];
    const float* cnb  = (const float*)d_in[9];
    const float* ow   = (const float*)d_in[10];
    const float* ob   = (const float*)d_in[11];
    const float* glw  = (const float*)d_in[12];
    const float* glb  = (const float*)d_in[13];

    char* ws = (char*)d_ws;
    size_t off = 0;
    unsigned short* left_t  = (unsigned short*)(ws + off); off += (size_t)128 * NPIX * 2;
    unsigned short* right_t = (unsigned short*)(ws + off); off += (size_t)128 * NPIX * 2;
    unsigned short* gate_o  = (unsigned short*)(ws + off); off += (size_t)NPIX * 128 * 2;
    unsigned short* tri     = (unsigned short*)(ws + off); off += (size_t)128 * NPIX * 2;
    unsigned short* Wcat    = (unsigned short*)(ws + off); off += 640 * 128 * 2;
    unsigned short* Wout    = (unsigned short*)(ws + off); off += 128 * 128 * 2;
    float* bcat             = (float*)(ws + off);          off += 640 * 4;
    // total ws use: ~604.2 MB

    k_pack<<<320, 256, 0, stream>>>(pw, gw, glw, pb, gb, glb, ow, Wcat, bcat, Wout);
    k_lnproj<<<NPIX / 64, 256, 0, stream>>>(act, mask, lnw, lnb, Wcat, bcat,
                                            left_t, right_t, gate_o);
    k_tri<<<128 * 36, 256, 0, stream>>>(left_t, right_t, tri);
    k_final<<<NRES * 6, 256, 0, stream>>>(tri, gate_o, cnw, cnb, Wout, ob, (float*)d_out);
}